// Round 3
// baseline (15566.226 us; speedup 1.0000x reference)
//
#include <hip/hip_runtime.h>
#include <math.h>

#define N_NODES 60000
#define N_EDGES 360000
#define N_GRAPH 64
#define HID 512
#define NCLS 1000
#define BN_EPS 1e-5f
#define NS ((size_t)N_NODES * HID)

static __device__ __forceinline__ unsigned short f2bf(float f) {
  unsigned u = __float_as_uint(f);
  unsigned r = (u + 0x7fffu + ((u >> 16) & 1u)) >> 16;  // RNE
  return (unsigned short)r;
}
static __device__ __forceinline__ float bfLo(unsigned u) { return __uint_as_float(u << 16); }
static __device__ __forceinline__ float bfHi(unsigned u) { return __uint_as_float(u & 0xffff0000u); }
static __device__ __forceinline__ unsigned packbf(float a, float b) {
  return (unsigned)f2bf(a) | ((unsigned)f2bf(b) << 16);
}

__global__ void write_sentinel(float* out, float v) { out[0] = v; }

// ---------------------------------------------------------------------------
// Degree / CSR build
// ---------------------------------------------------------------------------
__global__ __launch_bounds__(256) void count_deg(const int* __restrict__ dst,
                                                 int* __restrict__ deg, int E) {
  int e = blockIdx.x * 256 + threadIdx.x;
  if (e < E) atomicAdd(&deg[dst[e]], 1);
}

__global__ __launch_bounds__(256) void make_invdeg(const int* __restrict__ deg,
                                                   float* __restrict__ inv, int n) {
  int i = blockIdx.x * 256 + threadIdx.x;
  if (i < n) inv[i] = 1.0f / fmaxf((float)deg[i], 1.0f);
}

// single-block exclusive scan: rowptr[0]=0, rowptr[i+1]=sum(deg[0..i])
__global__ __launch_bounds__(256) void scan_rowptr(const int* __restrict__ deg,
                                                   int* __restrict__ rowptr, int n) {
  __shared__ int sh[256];
  __shared__ int carry;
  if (threadIdx.x == 0) { carry = 0; rowptr[0] = 0; }
  __syncthreads();
  for (int base = 0; base < n; base += 256) {
    int i = base + threadIdx.x;
    int v = (i < n) ? deg[i] : 0;
    sh[threadIdx.x] = v;
    __syncthreads();
    for (int off = 1; off < 256; off <<= 1) {
      int t = (threadIdx.x >= off) ? sh[threadIdx.x - off] : 0;
      __syncthreads();
      sh[threadIdx.x] += t;
      __syncthreads();
    }
    if (i < n) rowptr[i + 1] = carry + sh[threadIdx.x];
    __syncthreads();
    if (threadIdx.x == 0) carry += sh[255];
    __syncthreads();
  }
}

__global__ __launch_bounds__(256) void fill_csr(const int* __restrict__ src,
                                                const int* __restrict__ dst,
                                                const int* __restrict__ rowptr,
                                                int* __restrict__ fillc,
                                                int* __restrict__ esrc, int E) {
  int e = blockIdx.x * 256 + threadIdx.x;
  if (e < E) {
    int d = dst[e];
    int pos = rowptr[d] + atomicAdd(&fillc[d], 1);
    esrc[pos] = src[e];
  }
}

__global__ __launch_bounds__(256) void bcount(const int* __restrict__ batch,
                                              float* __restrict__ bcnt, int n) {
  int i = blockIdx.x * 256 + threadIdx.x;
  if (i < n) atomicAdd(&bcnt[batch[i]], 1.0f);
}

// ---------------------------------------------------------------------------
// Row-strip GEMM: out[M x 512](bf16) = X[M x K] @ W[K x 512] (+ bias)
// X fp32 (xBf16=0) or bf16 (xBf16=1). BM=64, BN=512, BK=16, 256 thr, 4x4x8acc.
// In-place safe over X (block reads only its own 64 rows; reads consumed into
// LDS before the epilogue stores).
// ---------------------------------------------------------------------------
__global__ __launch_bounds__(256) void gemm_rowstrip(
    const void* __restrict__ Xv, int ldx, int K, int xBf16,
    const float* __restrict__ W, const float* __restrict__ bias,
    unsigned short* __restrict__ outB, int M) {
  __shared__ float As[16][64];
  __shared__ float Bs[16][512];
  const int tid = threadIdx.x;
  const int bm = blockIdx.x * 64;
  const int ty = tid >> 4, tx = tid & 15;
  const int lr = tid >> 2, lk = (tid & 3) * 4;
  const int xrow = bm + lr;
  float4 acc[4][8];
#pragma unroll
  for (int i = 0; i < 4; ++i)
#pragma unroll
    for (int j = 0; j < 8; ++j) acc[i][j] = make_float4(0.f, 0.f, 0.f, 0.f);

  for (int k0 = 0; k0 < K; k0 += 16) {
    float4 xv = make_float4(0.f, 0.f, 0.f, 0.f);
    if (xrow < M) {
      if (xBf16) {
        uint2 u = *(const uint2*)((const unsigned short*)Xv + (size_t)xrow * ldx + k0 + lk);
        xv = make_float4(bfLo(u.x), bfHi(u.x), bfLo(u.y), bfHi(u.y));
      } else {
        xv = *(const float4*)((const float*)Xv + (size_t)xrow * ldx + k0 + lk);
      }
    }
    float4 wv[8];
#pragma unroll
    for (int t = 0; t < 8; ++t) {
      int f = t * 256 + tid;  // [16 krows][128 col4]
      wv[t] = *(const float4*)(W + (size_t)(k0 + (f >> 7)) * 512 + (f & 127) * 4);
    }
    __syncthreads();
    As[lk + 0][lr] = xv.x; As[lk + 1][lr] = xv.y;
    As[lk + 2][lr] = xv.z; As[lk + 3][lr] = xv.w;
#pragma unroll
    for (int t = 0; t < 8; ++t) {
      int f = t * 256 + tid;
      *(float4*)(&Bs[f >> 7][(f & 127) * 4]) = wv[t];
    }
    __syncthreads();
#pragma unroll
    for (int k = 0; k < 16; ++k) {
      float4 a = *(const float4*)(&As[k][ty * 4]);
#pragma unroll
      for (int cb = 0; cb < 8; ++cb) {
        float4 b = *(const float4*)(&Bs[k][cb * 64 + tx * 4]);
        acc[0][cb].x += a.x * b.x; acc[0][cb].y += a.x * b.y;
        acc[0][cb].z += a.x * b.z; acc[0][cb].w += a.x * b.w;
        acc[1][cb].x += a.y * b.x; acc[1][cb].y += a.y * b.y;
        acc[1][cb].z += a.y * b.z; acc[1][cb].w += a.y * b.w;
        acc[2][cb].x += a.z * b.x; acc[2][cb].y += a.z * b.y;
        acc[2][cb].z += a.z * b.z; acc[2][cb].w += a.z * b.w;
        acc[3][cb].x += a.w * b.x; acc[3][cb].y += a.w * b.y;
        acc[3][cb].z += a.w * b.z; acc[3][cb].w += a.w * b.w;
      }
    }
  }

#pragma unroll
  for (int i = 0; i < 4; ++i) {
    int r = bm + ty * 4 + i;
    if (r >= M) continue;
#pragma unroll
    for (int cb = 0; cb < 8; ++cb) {
      int c = cb * 64 + tx * 4;
      float4 v = acc[i][cb];
      if (bias) {
        v.x += bias[c]; v.y += bias[c + 1]; v.z += bias[c + 2]; v.w += bias[c + 3];
      }
      uint2 o;
      o.x = packbf(v.x, v.y);
      o.y = packbf(v.z, v.w);
      *(uint2*)(outB + (size_t)r * 512 + c) = o;
    }
  }
}

// ---------------------------------------------------------------------------
// Fused aggregation + L2 row-norm (one wave per dst node, CSR gather):
//   row = Ya[d] + invdeg[d] * sum_{e in CSR[d]} Yb[esrc[e]]
//   Ya[d] = row / max(||row||, 1e-12)        (bf16 in/out, fp32 accum)
// ---------------------------------------------------------------------------
__global__ __launch_bounds__(256) void aggr_norm(
    unsigned short* __restrict__ Ya, const unsigned short* __restrict__ Yb,
    const int* __restrict__ rowptr, const int* __restrict__ esrc,
    const float* __restrict__ invdeg, int M) {
  int d = blockIdx.x * 4 + (threadIdx.x >> 6);
  int lane = threadIdx.x & 63;
  if (d >= M) return;
  float acc[8] = {0.f, 0.f, 0.f, 0.f, 0.f, 0.f, 0.f, 0.f};
  int beg = rowptr[d], end = rowptr[d + 1];
  for (int e = beg; e < end; ++e) {
    int s = esrc[e];
    uint4 u = *(const uint4*)(Yb + (size_t)s * 512 + lane * 8);
    acc[0] += bfLo(u.x); acc[1] += bfHi(u.x);
    acc[2] += bfLo(u.y); acc[3] += bfHi(u.y);
    acc[4] += bfLo(u.z); acc[5] += bfHi(u.z);
    acc[6] += bfLo(u.w); acc[7] += bfHi(u.w);
  }
  float iv = invdeg[d];
  uint4 a = *(const uint4*)(Ya + (size_t)d * 512 + lane * 8);
  float r0 = bfLo(a.x) + iv * acc[0], r1 = bfHi(a.x) + iv * acc[1];
  float r2 = bfLo(a.y) + iv * acc[2], r3 = bfHi(a.y) + iv * acc[3];
  float r4 = bfLo(a.z) + iv * acc[4], r5 = bfHi(a.z) + iv * acc[5];
  float r6 = bfLo(a.w) + iv * acc[6], r7 = bfHi(a.w) + iv * acc[7];
  float ss = r0 * r0 + r1 * r1 + r2 * r2 + r3 * r3
           + r4 * r4 + r5 * r5 + r6 * r6 + r7 * r7;
#pragma unroll
  for (int o = 32; o; o >>= 1) ss += __shfl_xor(ss, o, 64);
  float inv = 1.0f / fmaxf(sqrtf(ss), 1e-12f);
  uint4 o4;
  o4.x = packbf(r0 * inv, r1 * inv);
  o4.y = packbf(r2 * inv, r3 * inv);
  o4.z = packbf(r4 * inv, r5 * inv);
  o4.w = packbf(r6 * inv, r7 * inv);
  *(uint4*)(Ya + (size_t)d * 512 + lane * 8) = o4;
}

// ---------------------------------------------------------------------------
// BN stats over bf16: sums[0..511]=sum, sums[512..1023]=sumsq
// ---------------------------------------------------------------------------
__global__ __launch_bounds__(256) void bn_stats(const unsigned short* __restrict__ T,
                                                int M, float* __restrict__ sums) {
  const int t = threadIdx.x;
  int r0 = blockIdx.x * 128;
  int rend = min(r0 + 128, M);
  float s0 = 0.f, q0 = 0.f, s1 = 0.f, q1 = 0.f;
  for (int r = r0; r < rend; ++r) {
    float a = __uint_as_float((unsigned)T[(size_t)r * 512 + t] << 16);
    float b = __uint_as_float((unsigned)T[(size_t)r * 512 + t + 256] << 16);
    s0 += a; q0 += a * a; s1 += b; q1 += b * b;
  }
  atomicAdd(&sums[t], s0);
  atomicAdd(&sums[t + 256], s1);
  atomicAdd(&sums[512 + t], q0);
  atomicAdd(&sums[512 + t + 256], q1);
}

// BN apply + ReLU (+ optional residual); bf16 in/out, 2 cols per thread.
__global__ __launch_bounds__(256) void bn_apply(const unsigned short* __restrict__ U,
                                                unsigned short* __restrict__ H,
                                                const float* __restrict__ sums,
                                                const float* __restrict__ g,
                                                const float* __restrict__ be,
                                                int M, int residual) {
  size_t i2 = (size_t)blockIdx.x * 256 + threadIdx.x;
  if (i2 >= NS / 2) return;
  int c = ((int)(i2 & 255)) * 2;
  float invM = 1.0f / (float)M;
  float m0 = sums[c] * invM, m1 = sums[c + 1] * invM;
  float v0 = sums[512 + c] * invM - m0 * m0;
  float v1 = sums[512 + c + 1] * invM - m1 * m1;
  float k0 = rsqrtf(v0 + BN_EPS) * g[c], k1 = rsqrtf(v1 + BN_EPS) * g[c + 1];
  unsigned u = ((const unsigned*)U)[i2];
  float x0 = fmaxf((bfLo(u) - m0) * k0 + be[c], 0.f);
  float x1 = fmaxf((bfHi(u) - m1) * k1 + be[c + 1], 0.f);
  if (residual) {
    unsigned hv = ((const unsigned*)H)[i2];
    x0 += bfLo(hv);
    x1 += bfHi(hv);
  }
  ((unsigned*)H)[i2] = packbf(x0, x1);
}

// ---------------------------------------------------------------------------
// Attention-gated segment-sum pool (one wave per node, bf16 H)
// ---------------------------------------------------------------------------
__global__ __launch_bounds__(256) void att_pool(const unsigned short* __restrict__ H,
                                                const int* __restrict__ batch,
                                                const float* __restrict__ Watt,
                                                float* __restrict__ hg, int M) {
  int w = blockIdx.x * 4 + (threadIdx.x >> 6);
  int lane = threadIdx.x & 63;
  if (w >= M) return;
  uint4 u = *(const uint4*)(H + (size_t)w * 512 + lane * 8);
  float v[8] = {bfLo(u.x), bfHi(u.x), bfLo(u.y), bfHi(u.y),
                bfLo(u.z), bfHi(u.z), bfLo(u.w), bfHi(u.w)};
  float4 wa0 = *(const float4*)(Watt + lane * 8);
  float4 wa1 = *(const float4*)(Watt + lane * 8 + 4);
  float dot = v[0] * wa0.x + v[1] * wa0.y + v[2] * wa0.z + v[3] * wa0.w
            + v[4] * wa1.x + v[5] * wa1.y + v[6] * wa1.z + v[7] * wa1.w;
#pragma unroll
  for (int o = 32; o; o >>= 1) dot += __shfl_xor(dot, o, 64);
  float att = 1.0f / (1.0f + expf(-dot));
  float f = 0.5f * (1.0f + att);
  float* d = hg + (size_t)batch[w] * 512 + lane * 8;
#pragma unroll
  for (int j = 0; j < 8; ++j) atomicAdd(d + j, v[j] * f);
}

// ---------------------------------------------------------------------------
// Readout: out[g, n] = (hg[g]/bcnt[g]) . Wread[:, n]
// ---------------------------------------------------------------------------
__global__ __launch_bounds__(256) void readout(const float* __restrict__ hg,
                                               const float* __restrict__ bcnt,
                                               const float* __restrict__ Wr,
                                               float* __restrict__ out) {
  __shared__ float sh[HID];
  int g = blockIdx.x;
  int n = blockIdx.y * 256 + threadIdx.x;
  float inv = 1.0f / fmaxf(bcnt[g], 1.0f);
  for (int k = threadIdx.x; k < HID; k += 256) sh[k] = hg[(size_t)g * HID + k] * inv;
  __syncthreads();
  if (n < NCLS) {
    float acc = 0.f;
    for (int k = 0; k < HID; ++k) acc += sh[k] * Wr[(size_t)k * NCLS + n];
    out[(size_t)g * NCLS + n] = acc;
  }
}

// ---------------------------------------------------------------------------
extern "C" void kernel_launch(void* const* d_in, const int* in_sizes, int n_in,
                              void* d_out, int out_size, void* d_ws, size_t ws_size,
                              hipStream_t stream) {
  const float* x       = (const float*)d_in[0];
  const int*   ei      = (const int*)d_in[1];
  const int*   batch   = (const int*)d_in[2];
  const float* W_embed = (const float*)d_in[3];
  const float* W1      = (const float*)d_in[4];
  const float* b1      = (const float*)d_in[5];
  const float* g1      = (const float*)d_in[6];
  const float* be1     = (const float*)d_in[7];
  const float* W2      = (const float*)d_in[8];
  const float* b2      = (const float*)d_in[9];
  const float* g2      = (const float*)d_in[10];
  const float* be2     = (const float*)d_in[11];
  const float* Watt    = (const float*)d_in[12];
  const float* Wread   = (const float*)d_in[13];
  float* out = (float*)d_out;

  const int* srcIdx = ei;
  const int* dstIdx = ei + N_EDGES;

  char* p = (char*)d_ws;
  unsigned short* B0 = (unsigned short*)p; p += NS * 2;   // h (residual)
  unsigned short* B1 = (unsigned short*)p; p += NS * 2;   // Ya / T
  unsigned short* B2 = (unsigned short*)p; p += NS * 2;   // Yb
  float* hg     = (float*)p; p += (size_t)N_GRAPH * HID * 4;
  float* sums   = (float*)p; p += 1024 * 4;
  float* invdeg = (float*)p; p += (size_t)N_NODES * 4;
  float* bcnt   = (float*)p; p += 256;
  int* deg      = (int*)p;   p += (size_t)N_NODES * 4;
  int* fillc    = (int*)p;   p += (size_t)N_NODES * 4;
  int* esrc     = (int*)p;   p += (size_t)N_EDGES * 4;
  int* rowptr   = (int*)p;   p += (size_t)(N_NODES + 1) * 4;
  size_t need = (size_t)(p - (char*)d_ws);
  if (ws_size < need) {  // diagnostic: out[0] = bytes needed
    write_sentinel<<<1, 1, 0, stream>>>(out, (float)need);
    return;
  }

  // ---- CSR build
  hipMemsetAsync(deg, 0, N_NODES * sizeof(int), stream);
  hipMemsetAsync(fillc, 0, N_NODES * sizeof(int), stream);
  count_deg<<<(N_EDGES + 255) / 256, 256, 0, stream>>>(dstIdx, deg, N_EDGES);
  make_invdeg<<<(N_NODES + 255) / 256, 256, 0, stream>>>(deg, invdeg, N_NODES);
  scan_rowptr<<<1, 256, 0, stream>>>(deg, rowptr, N_NODES);
  fill_csr<<<(N_EDGES + 255) / 256, 256, 0, stream>>>(srcIdx, dstIdx, rowptr, fillc,
                                                      esrc, N_EDGES);

  const int ggrid = (N_NODES + 63) / 64;        // 938
  const int ngrid = (N_NODES + 3) / 4;          // wave-per-node kernels
  const int egrid = (int)((NS / 2 + 255) / 256);

  // h = x @ W_embed  (fp32 in, bf16 out)
  gemm_rowstrip<<<ggrid, 256, 0, stream>>>(x, 256, 256, 0, W_embed, nullptr,
                                           B0, N_NODES);

  for (int l = 0; l < 3; ++l) {
    const float* Wl1 = W1 + (size_t)l * 1024 * 512;
    const float* Wl2 = W2 + (size_t)l * 1024 * 512;
    // ---- SAGE 1: T = relu(bn(norm(h@Wa1 + mean_aggr(h@Wb1) + b1)))
    gemm_rowstrip<<<ggrid, 256, 0, stream>>>(B0, 512, 512, 1, Wl1 + 512 * 512,
                                             nullptr, B2, N_NODES);   // Yb
    gemm_rowstrip<<<ggrid, 256, 0, stream>>>(B0, 512, 512, 1, Wl1,
                                             b1 + l * 512, B1, N_NODES);  // Ya
    aggr_norm<<<ngrid, 256, 0, stream>>>(B1, B2, rowptr, esrc, invdeg, N_NODES);
    hipMemsetAsync(sums, 0, 1024 * sizeof(float), stream);
    bn_stats<<<(N_NODES + 127) / 128, 256, 0, stream>>>(B1, N_NODES, sums);
    bn_apply<<<egrid, 256, 0, stream>>>(B1, B1, sums, g1 + l * 512,
                                        be1 + l * 512, N_NODES, 0);
    // ---- SAGE 2 + residual: h += relu(bn(norm(T@Wa2 + mean_aggr(T@Wb2) + b2)))
    gemm_rowstrip<<<ggrid, 256, 0, stream>>>(B1, 512, 512, 1, Wl2 + 512 * 512,
                                             nullptr, B2, N_NODES);   // Yb
    gemm_rowstrip<<<ggrid, 256, 0, stream>>>(B1, 512, 512, 1, Wl2,
                                             b2 + l * 512, B1, N_NODES);  // in-place
    aggr_norm<<<ngrid, 256, 0, stream>>>(B1, B2, rowptr, esrc, invdeg, N_NODES);
    hipMemsetAsync(sums, 0, 1024 * sizeof(float), stream);
    bn_stats<<<(N_NODES + 127) / 128, 256, 0, stream>>>(B1, N_NODES, sums);
    bn_apply<<<egrid, 256, 0, stream>>>(B1, B0, sums, g2 + l * 512,
                                        be2 + l * 512, N_NODES, 1);
  }

  // ---- pooling + readout
  hipMemsetAsync(hg, 0, (size_t)N_GRAPH * HID * sizeof(float), stream);
  hipMemsetAsync(bcnt, 0, N_GRAPH * sizeof(float), stream);
  bcount<<<(N_NODES + 255) / 256, 256, 0, stream>>>(batch, bcnt, N_NODES);
  att_pool<<<ngrid, 256, 0, stream>>>(B0, batch, Watt, hg, N_NODES);
  readout<<<dim3(N_GRAPH, 4), 256, 0, stream>>>(hg, bcnt, Wread, out);
}

// Round 5
// 4732.388 us; speedup vs baseline: 3.2893x; 3.2893x over previous
//
#include <hip/hip_runtime.h>
#include <math.h>

#define N_NODES 60000
#define N_EDGES 360000
#define N_GRAPH 64
#define HID 512
#define NCLS 1000
#define BN_EPS 1e-5f
#define NS ((size_t)N_NODES * HID)

typedef __bf16 bf16x8 __attribute__((ext_vector_type(8)));
typedef float f32x4 __attribute__((ext_vector_type(4)));

static __device__ __forceinline__ unsigned short f2bf(float f) {
  unsigned u = __float_as_uint(f);
  unsigned r = (u + 0x7fffu + ((u >> 16) & 1u)) >> 16;  // RNE
  return (unsigned short)r;
}
static __device__ __forceinline__ float bfLo(unsigned u) { return __uint_as_float(u << 16); }
static __device__ __forceinline__ float bfHi(unsigned u) { return __uint_as_float(u & 0xffff0000u); }
static __device__ __forceinline__ unsigned packbf(float a, float b) {
  return (unsigned)f2bf(a) | ((unsigned)f2bf(b) << 16);
}

__global__ void write_sentinel(float* out, float v) { out[0] = v; }

// ---------------------------------------------------------------------------
// Weight fp32 -> bf16 transpose: Wt[n][k] = bf16(W[k][n]).  32x32 tiles.
// ---------------------------------------------------------------------------
__global__ __launch_bounds__(256) void wtrans(const float* __restrict__ W,
                                              unsigned short* __restrict__ Wt,
                                              int K, int N) {
  __shared__ float sh[32][33];
  int kt = blockIdx.x * 32, nt = blockIdx.y * 32;
  int tx = threadIdx.x & 31, ty = threadIdx.x >> 5;  // ty 0..7
#pragma unroll
  for (int i = 0; i < 4; ++i)
    sh[ty + i * 8][tx] = W[(size_t)(kt + ty + i * 8) * N + nt + tx];
  __syncthreads();
#pragma unroll
  for (int i = 0; i < 4; ++i)
    Wt[(size_t)(nt + ty + i * 8) * K + kt + tx] = f2bf(sh[tx][ty + i * 8]);
}

// ---------------------------------------------------------------------------
// Degree / CSR build
// ---------------------------------------------------------------------------
__global__ __launch_bounds__(256) void count_deg(const int* __restrict__ dst,
                                                 int* __restrict__ deg, int E) {
  int e = blockIdx.x * 256 + threadIdx.x;
  if (e < E) atomicAdd(&deg[dst[e]], 1);
}

__global__ __launch_bounds__(256) void make_invdeg(const int* __restrict__ deg,
                                                   float* __restrict__ inv, int n) {
  int i = blockIdx.x * 256 + threadIdx.x;
  if (i < n) inv[i] = 1.0f / fmaxf((float)deg[i], 1.0f);
}

__global__ __launch_bounds__(256) void scan_rowptr(const int* __restrict__ deg,
                                                   int* __restrict__ rowptr, int n) {
  __shared__ int sh[256];
  __shared__ int carry;
  if (threadIdx.x == 0) { carry = 0; rowptr[0] = 0; }
  __syncthreads();
  for (int base = 0; base < n; base += 256) {
    int i = base + threadIdx.x;
    int v = (i < n) ? deg[i] : 0;
    sh[threadIdx.x] = v;
    __syncthreads();
    for (int off = 1; off < 256; off <<= 1) {
      int t = (threadIdx.x >= off) ? sh[threadIdx.x - off] : 0;
      __syncthreads();
      sh[threadIdx.x] += t;
      __syncthreads();
    }
    if (i < n) rowptr[i + 1] = carry + sh[threadIdx.x];
    __syncthreads();
    if (threadIdx.x == 0) carry += sh[255];
    __syncthreads();
  }
}

__global__ __launch_bounds__(256) void fill_csr(const int* __restrict__ src,
                                                const int* __restrict__ dst,
                                                const int* __restrict__ rowptr,
                                                int* __restrict__ fillc,
                                                int* __restrict__ esrc, int E) {
  int e = blockIdx.x * 256 + threadIdx.x;
  if (e < E) {
    int d = dst[e];
    int pos = rowptr[d] + atomicAdd(&fillc[d], 1);
    esrc[pos] = src[e];
  }
}

__global__ __launch_bounds__(256) void bcount(const int* __restrict__ batch,
                                              float* __restrict__ bcnt, int n) {
  int i = blockIdx.x * 256 + threadIdx.x;
  if (i < n) atomicAdd(&bcnt[batch[i]], 1.0f);
}

// ---------------------------------------------------------------------------
// MFMA GEMM, full-row-strip (in-place safe): out[M x 512](bf16) =
//   X[M x K] @ W[K x 512] (+ bias).  Wt = W^T in bf16: [512][ldw].
// BM=64, BN=512 (grid.y==1!), BK=32, 4 waves x (4x8) mfma_f32_16x16x32_bf16.
// A block reads ONLY rows [bm, bm+64) of X, fully staged to LDS before the
// epilogue stores those same rows -> X may alias outB.
// ---------------------------------------------------------------------------
__global__ __launch_bounds__(256) void gemm_mfma(
    const void* __restrict__ Xv, int ldx, int K, int xBf16,
    const unsigned short* __restrict__ Wt, int ldw,
    const float* __restrict__ bias,
    unsigned short* __restrict__ outB, int M) {
  __shared__ __align__(16) unsigned short As[64][40];
  __shared__ __align__(16) unsigned short Bs[512][40];
  const int tid = threadIdx.x;
  const int bm = blockIdx.x * 64;
  const int wv = tid >> 6, lane = tid & 63;
  const int lm = lane & 15, lk = (lane >> 4) * 8;

  f32x4 zero;
  zero[0] = 0.f; zero[1] = 0.f; zero[2] = 0.f; zero[3] = 0.f;
  f32x4 acc[4][8];
#pragma unroll
  for (int i = 0; i < 4; ++i)
#pragma unroll
    for (int j = 0; j < 8; ++j) acc[i][j] = zero;

  const int arow = tid >> 2, aseg = (tid & 3) * 8;  // A loader
  for (int kt = 0; kt < K; kt += 32) {
    // stage A (64 x 32) + B (512 x 32)
    uint4 av = make_uint4(0, 0, 0, 0);
    {
      int gr = bm + arow;
      if (gr < M) {
        if (xBf16) {
          av = *(const uint4*)((const unsigned short*)Xv + (size_t)gr * ldx + kt + aseg);
        } else {
          const float* xp = (const float*)Xv + (size_t)gr * ldx + kt + aseg;
          float4 f0 = *(const float4*)xp;
          float4 f1 = *(const float4*)(xp + 4);
          av.x = packbf(f0.x, f0.y); av.y = packbf(f0.z, f0.w);
          av.z = packbf(f1.x, f1.y); av.w = packbf(f1.z, f1.w);
        }
      }
    }
    uint4 bv[8];
#pragma unroll
    for (int r = 0; r < 8; ++r) {
      int idx = r * 256 + tid;
      bv[r] = *(const uint4*)(Wt + (size_t)(idx >> 2) * ldw + kt + (idx & 3) * 8);
    }
    __syncthreads();
    *(uint4*)(&As[arow][aseg]) = av;
#pragma unroll
    for (int r = 0; r < 8; ++r) {
      int idx = r * 256 + tid;
      *(uint4*)(&Bs[idx >> 2][(idx & 3) * 8]) = bv[r];
    }
    __syncthreads();
    bf16x8 af[4], bfr[8];
#pragma unroll
    for (int i = 0; i < 4; ++i) af[i] = *(const bf16x8*)(&As[i * 16 + lm][lk]);
#pragma unroll
    for (int j = 0; j < 8; ++j)
      bfr[j] = *(const bf16x8*)(&Bs[wv * 128 + j * 16 + lm][lk]);
#pragma unroll
    for (int i = 0; i < 4; ++i)
#pragma unroll
      for (int j = 0; j < 8; ++j)
        acc[i][j] = __builtin_amdgcn_mfma_f32_16x16x32_bf16(af[i], bfr[j], acc[i][j], 0, 0, 0);
  }

  const int qr = (lane >> 4) * 4;
#pragma unroll
  for (int j = 0; j < 8; ++j) {
    int col = wv * 128 + j * 16 + lm;
    float bvv = bias ? bias[col] : 0.f;
#pragma unroll
    for (int i = 0; i < 4; ++i) {
      int rbase = bm + i * 16 + qr;
#pragma unroll
      for (int r = 0; r < 4; ++r) {
        int row = rbase + r;
        if (row < M) outB[(size_t)row * 512 + col] = f2bf(acc[i][j][r] + bvv);
      }
    }
  }
}

// ---------------------------------------------------------------------------
// Fused aggregation + L2 row-norm (one wave per dst node, CSR gather):
//   row = Ya[d] + invdeg[d] * sum_{e in CSR[d]} Yb[esrc[e]];  Ya[d] = row/||row||
// ---------------------------------------------------------------------------
__global__ __launch_bounds__(256) void aggr_norm(
    unsigned short* __restrict__ Ya, const unsigned short* __restrict__ Yb,
    const int* __restrict__ rowptr, const int* __restrict__ esrc,
    const float* __restrict__ invdeg, int M) {
  int d = blockIdx.x * 4 + (threadIdx.x >> 6);
  int lane = threadIdx.x & 63;
  if (d >= M) return;
  float acc[8] = {0.f, 0.f, 0.f, 0.f, 0.f, 0.f, 0.f, 0.f};
  int beg = rowptr[d], end = rowptr[d + 1];
  for (int e = beg; e < end; ++e) {
    int s = esrc[e];
    uint4 u = *(const uint4*)(Yb + (size_t)s * 512 + lane * 8);
    acc[0] += bfLo(u.x); acc[1] += bfHi(u.x);
    acc[2] += bfLo(u.y); acc[3] += bfHi(u.y);
    acc[4] += bfLo(u.z); acc[5] += bfHi(u.z);
    acc[6] += bfLo(u.w); acc[7] += bfHi(u.w);
  }
  float iv = invdeg[d];
  uint4 a = *(const uint4*)(Ya + (size_t)d * 512 + lane * 8);
  float r0 = bfLo(a.x) + iv * acc[0], r1 = bfHi(a.x) + iv * acc[1];
  float r2 = bfLo(a.y) + iv * acc[2], r3 = bfHi(a.y) + iv * acc[3];
  float r4 = bfLo(a.z) + iv * acc[4], r5 = bfHi(a.z) + iv * acc[5];
  float r6 = bfLo(a.w) + iv * acc[6], r7 = bfHi(a.w) + iv * acc[7];
  float ss = r0 * r0 + r1 * r1 + r2 * r2 + r3 * r3
           + r4 * r4 + r5 * r5 + r6 * r6 + r7 * r7;
#pragma unroll
  for (int o = 32; o; o >>= 1) ss += __shfl_xor(ss, o, 64);
  float inv = 1.0f / fmaxf(sqrtf(ss), 1e-12f);
  uint4 o4;
  o4.x = packbf(r0 * inv, r1 * inv);
  o4.y = packbf(r2 * inv, r3 * inv);
  o4.z = packbf(r4 * inv, r5 * inv);
  o4.w = packbf(r6 * inv, r7 * inv);
  *(uint4*)(Ya + (size_t)d * 512 + lane * 8) = o4;
}

// ---------------------------------------------------------------------------
// BN stats over bf16: sums[0..511]=sum, sums[512..1023]=sumsq
// ---------------------------------------------------------------------------
__global__ __launch_bounds__(256) void bn_stats(const unsigned short* __restrict__ T,
                                                int M, float* __restrict__ sums) {
  const int t = threadIdx.x;
  int r0 = blockIdx.x * 128;
  int rend = min(r0 + 128, M);
  float s0 = 0.f, q0 = 0.f, s1 = 0.f, q1 = 0.f;
  for (int r = r0; r < rend; ++r) {
    float a = __uint_as_float((unsigned)T[(size_t)r * 512 + t] << 16);
    float b = __uint_as_float((unsigned)T[(size_t)r * 512 + t + 256] << 16);
    s0 += a; q0 += a * a; s1 += b; q1 += b * b;
  }
  atomicAdd(&sums[t], s0);
  atomicAdd(&sums[t + 256], s1);
  atomicAdd(&sums[512 + t], q0);
  atomicAdd(&sums[512 + t + 256], q1);
}

// BN apply + ReLU (+ optional residual); bf16 in/out, 2 cols per thread.
__global__ __launch_bounds__(256) void bn_apply(const unsigned short* __restrict__ U,
                                                unsigned short* __restrict__ H,
                                                const float* __restrict__ sums,
                                                const float* __restrict__ g,
                                                const float* __restrict__ be,
                                                int M, int residual) {
  size_t i2 = (size_t)blockIdx.x * 256 + threadIdx.x;
  if (i2 >= NS / 2) return;
  int c = ((int)(i2 & 255)) * 2;
  float invM = 1.0f / (float)M;
  float m0 = sums[c] * invM, m1 = sums[c + 1] * invM;
  float v0 = sums[512 + c] * invM - m0 * m0;
  float v1 = sums[512 + c + 1] * invM - m1 * m1;
  float k0 = rsqrtf(v0 + BN_EPS) * g[c], k1 = rsqrtf(v1 + BN_EPS) * g[c + 1];
  unsigned u = ((const unsigned*)U)[i2];
  float x0 = fmaxf((bfLo(u) - m0) * k0 + be[c], 0.f);
  float x1 = fmaxf((bfHi(u) - m1) * k1 + be[c + 1], 0.f);
  if (residual) {
    unsigned hv = ((const unsigned*)H)[i2];
    x0 += bfLo(hv);
    x1 += bfHi(hv);
  }
  ((unsigned*)H)[i2] = packbf(x0, x1);
}

// ---------------------------------------------------------------------------
// Attention pool, sorted-batch segmented version.
// ---------------------------------------------------------------------------
__global__ __launch_bounds__(256) void att_pool2(const unsigned short* __restrict__ H,
                                                 const int* __restrict__ batch,
                                                 const float* __restrict__ Watt,
                                                 float* __restrict__ hg, int M) {
  __shared__ float fsh[256];
  __shared__ int bsh[256];
  __shared__ float wsh[512];
  const int tid = threadIdx.x;
  const int base = blockIdx.x * 256;
  wsh[tid] = Watt[tid];
  wsh[tid + 256] = Watt[tid + 256];
  bsh[tid] = (base + tid < M) ? batch[base + tid] : -1;
  __syncthreads();
  const int wv = tid >> 6, lane = tid & 63;
  for (int i = wv; i < 256; i += 4) {
    int node = base + i;
    float dot = 0.f;
    if (node < M) {
      uint4 u = *(const uint4*)(H + (size_t)node * 512 + lane * 8);
      const float* w8 = &wsh[lane * 8];
      dot = bfLo(u.x) * w8[0] + bfHi(u.x) * w8[1]
          + bfLo(u.y) * w8[2] + bfHi(u.y) * w8[3]
          + bfLo(u.z) * w8[4] + bfHi(u.z) * w8[5]
          + bfLo(u.w) * w8[6] + bfHi(u.w) * w8[7];
    }
#pragma unroll
    for (int o = 32; o; o >>= 1) dot += __shfl_xor(dot, o, 64);
    if (lane == 0) fsh[i] = 0.5f * (1.0f + 1.0f / (1.0f + expf(-dot)));
  }
  __syncthreads();
  float a0 = 0.f, a1 = 0.f;
  int cur = bsh[0];
  for (int i = 0; i < 256; ++i) {
    int node = base + i;
    if (node >= M) break;
    int b = bsh[i];
    if (b != cur) {
      atomicAdd(&hg[(size_t)cur * 512 + tid * 2], a0);
      atomicAdd(&hg[(size_t)cur * 512 + tid * 2 + 1], a1);
      a0 = a1 = 0.f;
      cur = b;
    }
    unsigned u = *(const unsigned*)(H + (size_t)node * 512 + tid * 2);
    float f = fsh[i];
    a0 += bfLo(u) * f;
    a1 += bfHi(u) * f;
  }
  if (cur >= 0) {
    atomicAdd(&hg[(size_t)cur * 512 + tid * 2], a0);
    atomicAdd(&hg[(size_t)cur * 512 + tid * 2 + 1], a1);
  }
}

// ---------------------------------------------------------------------------
// Readout: out[g, n] = (hg[g]/bcnt[g]) . Wread[:, n]
// ---------------------------------------------------------------------------
__global__ __launch_bounds__(256) void readout(const float* __restrict__ hg,
                                               const float* __restrict__ bcnt,
                                               const float* __restrict__ Wr,
                                               float* __restrict__ out) {
  __shared__ float sh[HID];
  int g = blockIdx.x;
  int n = blockIdx.y * 256 + threadIdx.x;
  float inv = 1.0f / fmaxf(bcnt[g], 1.0f);
  for (int k = threadIdx.x; k < HID; k += 256) sh[k] = hg[(size_t)g * HID + k] * inv;
  __syncthreads();
  if (n < NCLS) {
    float acc = 0.f;
    for (int k = 0; k < HID; ++k) acc += sh[k] * Wr[(size_t)k * NCLS + n];
    out[(size_t)g * NCLS + n] = acc;
  }
}

// ---------------------------------------------------------------------------
extern "C" void kernel_launch(void* const* d_in, const int* in_sizes, int n_in,
                              void* d_out, int out_size, void* d_ws, size_t ws_size,
                              hipStream_t stream) {
  const float* x       = (const float*)d_in[0];
  const int*   ei      = (const int*)d_in[1];
  const int*   batch   = (const int*)d_in[2];
  const float* W_embed = (const float*)d_in[3];
  const float* W1      = (const float*)d_in[4];
  const float* b1      = (const float*)d_in[5];
  const float* g1      = (const float*)d_in[6];
  const float* be1     = (const float*)d_in[7];
  const float* W2      = (const float*)d_in[8];
  const float* b2      = (const float*)d_in[9];
  const float* g2      = (const float*)d_in[10];
  const float* be2     = (const float*)d_in[11];
  const float* Watt    = (const float*)d_in[12];
  const float* Wread   = (const float*)d_in[13];
  float* out = (float*)d_out;

  const int* srcIdx = ei;
  const int* dstIdx = ei + N_EDGES;

  char* p = (char*)d_ws;
  unsigned short* B0 = (unsigned short*)p; p += NS * 2;   // h (residual)
  unsigned short* B1 = (unsigned short*)p; p += NS * 2;   // Ya / T
  unsigned short* B2 = (unsigned short*)p; p += NS * 2;   // Yb
  unsigned short* WtE = (unsigned short*)p; p += (size_t)512 * 256 * 2;
  unsigned short* Wt1 = (unsigned short*)p; p += (size_t)3 * 512 * 1024 * 2;
  unsigned short* Wt2 = (unsigned short*)p; p += (size_t)3 * 512 * 1024 * 2;
  float* hg     = (float*)p; p += (size_t)N_GRAPH * HID * 4;
  float* sums   = (float*)p; p += 1024 * 4;
  float* invdeg = (float*)p; p += (size_t)N_NODES * 4;
  float* bcnt   = (float*)p; p += 256;
  int* deg      = (int*)p;   p += (size_t)N_NODES * 4;
  int* fillc    = (int*)p;   p += (size_t)N_NODES * 4;
  int* esrc     = (int*)p;   p += (size_t)N_EDGES * 4;
  int* rowptr   = (int*)p;   p += (size_t)(N_NODES + 1) * 4;
  size_t need = (size_t)(p - (char*)d_ws);
  if (ws_size < need) {  // diagnostic sentinel
    write_sentinel<<<1, 1, 0, stream>>>(out, (float)need);
    return;
  }

  // ---- weight prep (fp32 -> bf16, transposed [N][K])
  wtrans<<<dim3(8, 16), 256, 0, stream>>>(W_embed, WtE, 256, 512);
  for (int l = 0; l < 3; ++l) {
    wtrans<<<dim3(32, 16), 256, 0, stream>>>(W1 + (size_t)l * 1024 * 512,
                                             Wt1 + (size_t)l * 512 * 1024, 1024, 512);
    wtrans<<<dim3(32, 16), 256, 0, stream>>>(W2 + (size_t)l * 1024 * 512,
                                             Wt2 + (size_t)l * 512 * 1024, 1024, 512);
  }

  // ---- CSR build
  hipMemsetAsync(deg, 0, N_NODES * sizeof(int), stream);
  hipMemsetAsync(fillc, 0, N_NODES * sizeof(int), stream);
  count_deg<<<(N_EDGES + 255) / 256, 256, 0, stream>>>(dstIdx, deg, N_EDGES);
  make_invdeg<<<(N_NODES + 255) / 256, 256, 0, stream>>>(deg, invdeg, N_NODES);
  scan_rowptr<<<1, 256, 0, stream>>>(deg, rowptr, N_NODES);
  fill_csr<<<(N_EDGES + 255) / 256, 256, 0, stream>>>(srcIdx, dstIdx, rowptr, fillc,
                                                      esrc, N_EDGES);

  const int mgrid = (N_NODES + 63) / 64;   // 938, grid.y == 1 (in-place safety)
  const int ngrid = (N_NODES + 3) / 4;
  const int egrid = (int)((NS / 2 + 255) / 256);

  // h = x @ W_embed
  gemm_mfma<<<mgrid, 256, 0, stream>>>(x, 256, 256, 0, WtE, 256, nullptr, B0, N_NODES);

  for (int l = 0; l < 3; ++l) {
    const unsigned short* Wt1l = Wt1 + (size_t)l * 512 * 1024;
    const unsigned short* Wt2l = Wt2 + (size_t)l * 512 * 1024;
    // ---- SAGE 1
    gemm_mfma<<<mgrid, 256, 0, stream>>>(B0, 512, 512, 1, Wt1l + 512, 1024,
                                         nullptr, B2, N_NODES);        // Yb = h@Wb1
    gemm_mfma<<<mgrid, 256, 0, stream>>>(B0, 512, 512, 1, Wt1l, 1024,
                                         b1 + l * 512, B1, N_NODES);   // Ya = h@Wa1+b
    aggr_norm<<<ngrid, 256, 0, stream>>>(B1, B2, rowptr, esrc, invdeg, N_NODES);
    hipMemsetAsync(sums, 0, 1024 * sizeof(float), stream);
    bn_stats<<<(N_NODES + 127) / 128, 256, 0, stream>>>(B1, N_NODES, sums);
    bn_apply<<<egrid, 256, 0, stream>>>(B1, B1, sums, g1 + l * 512,
                                        be1 + l * 512, N_NODES, 0);
    // ---- SAGE 2 + residual
    gemm_mfma<<<mgrid, 256, 0, stream>>>(B1, 512, 512, 1, Wt2l + 512, 1024,
                                         nullptr, B2, N_NODES);        // Yb
    gemm_mfma<<<mgrid, 256, 0, stream>>>(B1, 512, 512, 1, Wt2l, 1024,
                                         b2 + l * 512, B1, N_NODES);   // in-place, safe
    aggr_norm<<<ngrid, 256, 0, stream>>>(B1, B2, rowptr, esrc, invdeg, N_NODES);
    hipMemsetAsync(sums, 0, 1024 * sizeof(float), stream);
    bn_stats<<<(N_NODES + 127) / 128, 256, 0, stream>>>(B1, N_NODES, sums);
    bn_apply<<<egrid, 256, 0, stream>>>(B1, B0, sums, g2 + l * 512,
                                        be2 + l * 512, N_NODES, 1);
  }

  // ---- pooling + readout
  hipMemsetAsync(hg, 0, (size_t)N_GRAPH * HID * sizeof(float), stream);
  hipMemsetAsync(bcnt, 0, N_GRAPH * sizeof(float), stream);
  bcount<<<(N_NODES + 255) / 256, 256, 0, stream>>>(batch, bcnt, N_NODES);
  att_pool2<<<(N_NODES + 255) / 256, 256, 0, stream>>>(B0, batch, Watt, hg, N_NODES);
  readout<<<dim3(N_GRAPH, 4), 256, 0, stream>>>(hg, bcnt, Wread, out);
}

// Round 6
// 2559.561 us; speedup vs baseline: 6.0816x; 1.8489x over previous
//
#include <hip/hip_runtime.h>
#include <math.h>

#define N_NODES 60000
#define N_EDGES 360000
#define N_GRAPH 64
#define HID 512
#define NCLS 1000
#define BN_EPS 1e-5f
#define NS ((size_t)N_NODES * HID)
#define NB 235  // (N_NODES + 255) / 256

typedef __bf16 bf16x8 __attribute__((ext_vector_type(8)));
typedef float f32x4 __attribute__((ext_vector_type(4)));

static __device__ __forceinline__ unsigned short f2bf(float f) {
  unsigned u = __float_as_uint(f);
  unsigned r = (u + 0x7fffu + ((u >> 16) & 1u)) >> 16;  // RNE
  return (unsigned short)r;
}
static __device__ __forceinline__ float bfLo(unsigned u) { return __uint_as_float(u << 16); }
static __device__ __forceinline__ float bfHi(unsigned u) { return __uint_as_float(u & 0xffff0000u); }
static __device__ __forceinline__ unsigned packbf(float a, float b) {
  return (unsigned)f2bf(a) | ((unsigned)f2bf(b) << 16);
}

__global__ void write_sentinel(float* out, float v) { out[0] = v; }

// ---------------------------------------------------------------------------
// Weight fp32 -> bf16 transpose: Wt[n][k] = bf16(W[k][n]).  32x32 tiles.
// ---------------------------------------------------------------------------
__global__ __launch_bounds__(256) void wtrans(const float* __restrict__ W,
                                              unsigned short* __restrict__ Wt,
                                              int K, int N) {
  __shared__ float sh[32][33];
  int kt = blockIdx.x * 32, nt = blockIdx.y * 32;
  int tx = threadIdx.x & 31, ty = threadIdx.x >> 5;  // ty 0..7
#pragma unroll
  for (int i = 0; i < 4; ++i)
    sh[ty + i * 8][tx] = W[(size_t)(kt + ty + i * 8) * N + nt + tx];
  __syncthreads();
#pragma unroll
  for (int i = 0; i < 4; ++i)
    Wt[(size_t)(nt + ty + i * 8) * K + kt + tx] = f2bf(sh[tx][ty + i * 8]);
}

// ---------------------------------------------------------------------------
// Degree / CSR build
// ---------------------------------------------------------------------------
__global__ __launch_bounds__(256) void count_deg(const int* __restrict__ dst,
                                                 int* __restrict__ deg, int E) {
  int e = blockIdx.x * 256 + threadIdx.x;
  if (e < E) atomicAdd(&deg[dst[e]], 1);
}

__global__ __launch_bounds__(256) void make_invdeg(const int* __restrict__ deg,
                                                   float* __restrict__ inv, int n) {
  int i = blockIdx.x * 256 + threadIdx.x;
  if (i < n) inv[i] = 1.0f / fmaxf((float)deg[i], 1.0f);
}

// ---- parallel 3-phase exclusive scan of deg -> rowptr -----------------------
__global__ __launch_bounds__(256) void scan_part(const int* __restrict__ deg,
                                                 int* __restrict__ bsum, int n) {
  __shared__ int sh[256];
  int i = blockIdx.x * 256 + threadIdx.x;
  sh[threadIdx.x] = (i < n) ? deg[i] : 0;
  __syncthreads();
  for (int off = 128; off; off >>= 1) {
    if (threadIdx.x < off) sh[threadIdx.x] += sh[threadIdx.x + off];
    __syncthreads();
  }
  if (threadIdx.x == 0) bsum[blockIdx.x] = sh[0];
}

__global__ __launch_bounds__(256) void scan_bsums(int* __restrict__ bsum, int nb) {
  __shared__ int sh[256];
  int t = threadIdx.x;
  int v = (t < nb) ? bsum[t] : 0;
  sh[t] = v;
  __syncthreads();
  for (int off = 1; off < 256; off <<= 1) {
    int u = (t >= off) ? sh[t - off] : 0;
    __syncthreads();
    sh[t] += u;
    __syncthreads();
  }
  if (t < nb) bsum[t] = sh[t] - v;  // exclusive
}

__global__ __launch_bounds__(256) void scan_final(const int* __restrict__ deg,
                                                  const int* __restrict__ bsum,
                                                  int* __restrict__ rowptr, int n) {
  __shared__ int sh[256];
  int t = threadIdx.x;
  int i = blockIdx.x * 256 + t;
  int v = (i < n) ? deg[i] : 0;
  sh[t] = v;
  __syncthreads();
  for (int off = 1; off < 256; off <<= 1) {
    int u = (t >= off) ? sh[t - off] : 0;
    __syncthreads();
    sh[t] += u;
    __syncthreads();
  }
  if (i < n) rowptr[i + 1] = bsum[blockIdx.x] + sh[t];
  if (i == 0) rowptr[0] = 0;
}

__global__ __launch_bounds__(256) void fill_csr(const int* __restrict__ src,
                                                const int* __restrict__ dst,
                                                const int* __restrict__ rowptr,
                                                int* __restrict__ fillc,
                                                int* __restrict__ esrc, int E) {
  int e = blockIdx.x * 256 + threadIdx.x;
  if (e < E) {
    int d = dst[e];
    int pos = rowptr[d] + atomicAdd(&fillc[d], 1);
    esrc[pos] = src[e];
  }
}

__global__ __launch_bounds__(256) void bcount(const int* __restrict__ batch,
                                              float* __restrict__ bcnt, int n) {
  int i = blockIdx.x * 256 + threadIdx.x;
  if (i < n) atomicAdd(&bcnt[batch[i]], 1.0f);
}

// ---------------------------------------------------------------------------
// MFMA GEMM, full-row-strip (in-place safe): out[M x 512](bf16) =
//   X[M x K] @ W[K x 512] (+ bias).  Wt = W^T bf16 [512][ldw].
// 512 threads = 8 waves; wave wv covers cols [wv*64, wv*64+64). BM=64, BK=32.
// A staged via LDS (shared by all waves); B fragments loaded DIRECTLY from
// global (Wt is ~1MB -> L2-resident; fragment = 16B contiguous run of Wt row).
// In-place safe: grid is 1-D row strips; A rows consumed into LDS behind a
// barrier before the epilogue stores those same rows.
// ---------------------------------------------------------------------------
__global__ __launch_bounds__(512) void gemm_mfma(
    const void* __restrict__ Xv, int ldx, int K, int xBf16,
    const unsigned short* __restrict__ Wt, int ldw,
    const float* __restrict__ bias,
    unsigned short* __restrict__ outB, int M) {
  __shared__ __align__(16) unsigned short As[64][40];
  const int tid = threadIdx.x;
  const int bm = blockIdx.x * 64;
  const int wv = tid >> 6, lane = tid & 63;
  const int lm = lane & 15, quad = lane >> 4, lk = quad * 8;
  const int cb = wv * 64;
  const int arow = tid >> 3, aseg = (tid & 7) * 4;  // A loader: 8B/thread

  f32x4 zero;
  zero[0] = 0.f; zero[1] = 0.f; zero[2] = 0.f; zero[3] = 0.f;
  f32x4 acc[4][4];
#pragma unroll
  for (int i = 0; i < 4; ++i)
#pragma unroll
    for (int j = 0; j < 4; ++j) acc[i][j] = zero;

  for (int kt = 0; kt < K; kt += 32) {
    uint2 av = make_uint2(0, 0);
    {
      int gr = bm + arow;
      if (gr < M) {
        if (xBf16) {
          av = *(const uint2*)((const unsigned short*)Xv + (size_t)gr * ldx + kt + aseg);
        } else {
          float4 f = *(const float4*)((const float*)Xv + (size_t)gr * ldx + kt + aseg);
          av.x = packbf(f.x, f.y);
          av.y = packbf(f.z, f.w);
        }
      }
    }
    bf16x8 bfr[4];
#pragma unroll
    for (int j = 0; j < 4; ++j)
      bfr[j] = *(const bf16x8*)(Wt + (size_t)(cb + j * 16 + lm) * ldw + kt + lk);
    __syncthreads();
    *(uint2*)(&As[arow][aseg]) = av;
    __syncthreads();
    bf16x8 af[4];
#pragma unroll
    for (int i = 0; i < 4; ++i) af[i] = *(const bf16x8*)(&As[i * 16 + lm][lk]);
#pragma unroll
    for (int i = 0; i < 4; ++i)
#pragma unroll
      for (int j = 0; j < 4; ++j)
        acc[i][j] = __builtin_amdgcn_mfma_f32_16x16x32_bf16(af[i], bfr[j], acc[i][j], 0, 0, 0);
  }

  const int qr = quad * 4;
#pragma unroll
  for (int j = 0; j < 4; ++j) {
    int col = cb + j * 16 + lm;
    float bvv = bias ? bias[col] : 0.f;
#pragma unroll
    for (int i = 0; i < 4; ++i) {
      int rbase = bm + i * 16 + qr;
#pragma unroll
      for (int r = 0; r < 4; ++r) {
        int row = rbase + r;
        if (row < M) outB[(size_t)row * 512 + col] = f2bf(acc[i][j][r] + bvv);
      }
    }
  }
}

// ---------------------------------------------------------------------------
// Fused aggregation + L2 row-norm (one wave per dst node, CSR gather):
//   row = Ya[d] + invdeg[d] * sum_{e in CSR[d]} Yb[esrc[e]];  Ya[d] = row/||row||
// ---------------------------------------------------------------------------
__global__ __launch_bounds__(256) void aggr_norm(
    unsigned short* __restrict__ Ya, const unsigned short* __restrict__ Yb,
    const int* __restrict__ rowptr, const int* __restrict__ esrc,
    const float* __restrict__ invdeg, int M) {
  int d = blockIdx.x * 4 + (threadIdx.x >> 6);
  int lane = threadIdx.x & 63;
  if (d >= M) return;
  float acc[8] = {0.f, 0.f, 0.f, 0.f, 0.f, 0.f, 0.f, 0.f};
  int beg = rowptr[d], end = rowptr[d + 1];
  for (int e = beg; e < end; ++e) {
    int s = esrc[e];
    uint4 u = *(const uint4*)(Yb + (size_t)s * 512 + lane * 8);
    acc[0] += bfLo(u.x); acc[1] += bfHi(u.x);
    acc[2] += bfLo(u.y); acc[3] += bfHi(u.y);
    acc[4] += bfLo(u.z); acc[5] += bfHi(u.z);
    acc[6] += bfLo(u.w); acc[7] += bfHi(u.w);
  }
  float iv = invdeg[d];
  uint4 a = *(const uint4*)(Ya + (size_t)d * 512 + lane * 8);
  float r0 = bfLo(a.x) + iv * acc[0], r1 = bfHi(a.x) + iv * acc[1];
  float r2 = bfLo(a.y) + iv * acc[2], r3 = bfHi(a.y) + iv * acc[3];
  float r4 = bfLo(a.z) + iv * acc[4], r5 = bfHi(a.z) + iv * acc[5];
  float r6 = bfLo(a.w) + iv * acc[6], r7 = bfHi(a.w) + iv * acc[7];
  float ss = r0 * r0 + r1 * r1 + r2 * r2 + r3 * r3
           + r4 * r4 + r5 * r5 + r6 * r6 + r7 * r7;
#pragma unroll
  for (int o = 32; o; o >>= 1) ss += __shfl_xor(ss, o, 64);
  float inv = 1.0f / fmaxf(sqrtf(ss), 1e-12f);
  uint4 o4;
  o4.x = packbf(r0 * inv, r1 * inv);
  o4.y = packbf(r2 * inv, r3 * inv);
  o4.z = packbf(r4 * inv, r5 * inv);
  o4.w = packbf(r6 * inv, r7 * inv);
  *(uint4*)(Ya + (size_t)d * 512 + lane * 8) = o4;
}

// ---------------------------------------------------------------------------
// BN stats over bf16: sums[0..511]=sum, sums[512..1023]=sumsq
// ---------------------------------------------------------------------------
__global__ __launch_bounds__(256) void bn_stats(const unsigned short* __restrict__ T,
                                                int M, float* __restrict__ sums) {
  const int t = threadIdx.x;
  int r0 = blockIdx.x * 128;
  int rend = min(r0 + 128, M);
  float s0 = 0.f, q0 = 0.f, s1 = 0.f, q1 = 0.f;
  for (int r = r0; r < rend; ++r) {
    float a = __uint_as_float((unsigned)T[(size_t)r * 512 + t] << 16);
    float b = __uint_as_float((unsigned)T[(size_t)r * 512 + t + 256] << 16);
    s0 += a; q0 += a * a; s1 += b; q1 += b * b;
  }
  atomicAdd(&sums[t], s0);
  atomicAdd(&sums[t + 256], s1);
  atomicAdd(&sums[512 + t], q0);
  atomicAdd(&sums[512 + t + 256], q1);
}

// BN apply + ReLU (+ optional residual); bf16 in/out, 2 cols per thread.
__global__ __launch_bounds__(256) void bn_apply(const unsigned short* __restrict__ U,
                                                unsigned short* __restrict__ H,
                                                const float* __restrict__ sums,
                                                const float* __restrict__ g,
                                                const float* __restrict__ be,
                                                int M, int residual) {
  size_t i2 = (size_t)blockIdx.x * 256 + threadIdx.x;
  if (i2 >= NS / 2) return;
  int c = ((int)(i2 & 255)) * 2;
  float invM = 1.0f / (float)M;
  float m0 = sums[c] * invM, m1 = sums[c + 1] * invM;
  float v0 = sums[512 + c] * invM - m0 * m0;
  float v1 = sums[512 + c + 1] * invM - m1 * m1;
  float k0 = rsqrtf(v0 + BN_EPS) * g[c], k1 = rsqrtf(v1 + BN_EPS) * g[c + 1];
  unsigned u = ((const unsigned*)U)[i2];
  float x0 = fmaxf((bfLo(u) - m0) * k0 + be[c], 0.f);
  float x1 = fmaxf((bfHi(u) - m1) * k1 + be[c + 1], 0.f);
  if (residual) {
    unsigned hv = ((const unsigned*)H)[i2];
    x0 += bfLo(hv);
    x1 += bfHi(hv);
  }
  ((unsigned*)H)[i2] = packbf(x0, x1);
}

// ---------------------------------------------------------------------------
// Attention pool, sorted-batch segmented version.
// ---------------------------------------------------------------------------
__global__ __launch_bounds__(256) void att_pool2(const unsigned short* __restrict__ H,
                                                 const int* __restrict__ batch,
                                                 const float* __restrict__ Watt,
                                                 float* __restrict__ hg, int M) {
  __shared__ float fsh[256];
  __shared__ int bsh[256];
  __shared__ float wsh[512];
  const int tid = threadIdx.x;
  const int base = blockIdx.x * 256;
  wsh[tid] = Watt[tid];
  wsh[tid + 256] = Watt[tid + 256];
  bsh[tid] = (base + tid < M) ? batch[base + tid] : -1;
  __syncthreads();
  const int wv = tid >> 6, lane = tid & 63;
  for (int i = wv; i < 256; i += 4) {
    int node = base + i;
    float dot = 0.f;
    if (node < M) {
      uint4 u = *(const uint4*)(H + (size_t)node * 512 + lane * 8);
      const float* w8 = &wsh[lane * 8];
      dot = bfLo(u.x) * w8[0] + bfHi(u.x) * w8[1]
          + bfLo(u.y) * w8[2] + bfHi(u.y) * w8[3]
          + bfLo(u.z) * w8[4] + bfHi(u.z) * w8[5]
          + bfLo(u.w) * w8[6] + bfHi(u.w) * w8[7];
    }
#pragma unroll
    for (int o = 32; o; o >>= 1) dot += __shfl_xor(dot, o, 64);
    if (lane == 0) fsh[i] = 0.5f * (1.0f + 1.0f / (1.0f + expf(-dot)));
  }
  __syncthreads();
  float a0 = 0.f, a1 = 0.f;
  int cur = bsh[0];
  for (int i = 0; i < 256; ++i) {
    int node = base + i;
    if (node >= M) break;
    int b = bsh[i];
    if (b != cur) {
      atomicAdd(&hg[(size_t)cur * 512 + tid * 2], a0);
      atomicAdd(&hg[(size_t)cur * 512 + tid * 2 + 1], a1);
      a0 = a1 = 0.f;
      cur = b;
    }
    unsigned u = *(const unsigned*)(H + (size_t)node * 512 + tid * 2);
    float f = fsh[i];
    a0 += bfLo(u) * f;
    a1 += bfHi(u) * f;
  }
  if (cur >= 0) {
    atomicAdd(&hg[(size_t)cur * 512 + tid * 2], a0);
    atomicAdd(&hg[(size_t)cur * 512 + tid * 2 + 1], a1);
  }
}

// ---------------------------------------------------------------------------
// Readout: out[g, n] = (hg[g]/bcnt[g]) . Wread[:, n]
// ---------------------------------------------------------------------------
__global__ __launch_bounds__(256) void readout(const float* __restrict__ hg,
                                               const float* __restrict__ bcnt,
                                               const float* __restrict__ Wr,
                                               float* __restrict__ out) {
  __shared__ float sh[HID];
  int g = blockIdx.x;
  int n = blockIdx.y * 256 + threadIdx.x;
  float inv = 1.0f / fmaxf(bcnt[g], 1.0f);
  for (int k = threadIdx.x; k < HID; k += 256) sh[k] = hg[(size_t)g * HID + k] * inv;
  __syncthreads();
  if (n < NCLS) {
    float acc = 0.f;
    for (int k = 0; k < HID; ++k) acc += sh[k] * Wr[(size_t)k * NCLS + n];
    out[(size_t)g * NCLS + n] = acc;
  }
}

// ---------------------------------------------------------------------------
extern "C" void kernel_launch(void* const* d_in, const int* in_sizes, int n_in,
                              void* d_out, int out_size, void* d_ws, size_t ws_size,
                              hipStream_t stream) {
  const float* x       = (const float*)d_in[0];
  const int*   ei      = (const int*)d_in[1];
  const int*   batch   = (const int*)d_in[2];
  const float* W_embed = (const float*)d_in[3];
  const float* W1      = (const float*)d_in[4];
  const float* b1      = (const float*)d_in[5];
  const float* g1      = (const float*)d_in[6];
  const float* be1     = (const float*)d_in[7];
  const float* W2      = (const float*)d_in[8];
  const float* b2      = (const float*)d_in[9];
  const float* g2      = (const float*)d_in[10];
  const float* be2     = (const float*)d_in[11];
  const float* Watt    = (const float*)d_in[12];
  const float* Wread   = (const float*)d_in[13];
  float* out = (float*)d_out;

  const int* srcIdx = ei;
  const int* dstIdx = ei + N_EDGES;

  char* p = (char*)d_ws;
  unsigned short* B0 = (unsigned short*)p; p += NS * 2;   // h (residual)
  unsigned short* B1 = (unsigned short*)p; p += NS * 2;   // Ya / T
  unsigned short* B2 = (unsigned short*)p; p += NS * 2;   // Yb
  unsigned short* WtE = (unsigned short*)p; p += (size_t)512 * 256 * 2;
  unsigned short* Wt1 = (unsigned short*)p; p += (size_t)3 * 512 * 1024 * 2;
  unsigned short* Wt2 = (unsigned short*)p; p += (size_t)3 * 512 * 1024 * 2;
  float* hg     = (float*)p; p += (size_t)N_GRAPH * HID * 4;
  float* sums   = (float*)p; p += 1024 * 4;
  float* invdeg = (float*)p; p += (size_t)N_NODES * 4;
  float* bcnt   = (float*)p; p += 256;
  int* deg      = (int*)p;   p += (size_t)N_NODES * 4;
  int* fillc    = (int*)p;   p += (size_t)N_NODES * 4;
  int* esrc     = (int*)p;   p += (size_t)N_EDGES * 4;
  int* rowptr   = (int*)p;   p += (size_t)(N_NODES + 1) * 4;
  int* bsum     = (int*)p;   p += (size_t)NB * 4;
  size_t need = (size_t)(p - (char*)d_ws);
  if (ws_size < need) {  // diagnostic sentinel
    write_sentinel<<<1, 1, 0, stream>>>(out, (float)need);
    return;
  }

  // ---- weight prep (fp32 -> bf16, transposed [N][K])
  wtrans<<<dim3(8, 16), 256, 0, stream>>>(W_embed, WtE, 256, 512);
  for (int l = 0; l < 3; ++l) {
    wtrans<<<dim3(32, 16), 256, 0, stream>>>(W1 + (size_t)l * 1024 * 512,
                                             Wt1 + (size_t)l * 512 * 1024, 1024, 512);
    wtrans<<<dim3(32, 16), 256, 0, stream>>>(W2 + (size_t)l * 1024 * 512,
                                             Wt2 + (size_t)l * 512 * 1024, 1024, 512);
  }

  // ---- CSR build (parallel scan)
  hipMemsetAsync(deg, 0, N_NODES * sizeof(int), stream);
  hipMemsetAsync(fillc, 0, N_NODES * sizeof(int), stream);
  count_deg<<<(N_EDGES + 255) / 256, 256, 0, stream>>>(dstIdx, deg, N_EDGES);
  make_invdeg<<<(N_NODES + 255) / 256, 256, 0, stream>>>(deg, invdeg, N_NODES);
  scan_part<<<NB, 256, 0, stream>>>(deg, bsum, N_NODES);
  scan_bsums<<<1, 256, 0, stream>>>(bsum, NB);
  scan_final<<<NB, 256, 0, stream>>>(deg, bsum, rowptr, N_NODES);
  fill_csr<<<(N_EDGES + 255) / 256, 256, 0, stream>>>(srcIdx, dstIdx, rowptr, fillc,
                                                      esrc, N_EDGES);

  const int mgrid = (N_NODES + 63) / 64;   // 938, grid.y == 1 (in-place safety)
  const int ngrid = (N_NODES + 3) / 4;
  const int egrid = (int)((NS / 2 + 255) / 256);

  // h = x @ W_embed
  gemm_mfma<<<mgrid, 512, 0, stream>>>(x, 256, 256, 0, WtE, 256, nullptr, B0, N_NODES);

  for (int l = 0; l < 3; ++l) {
    const unsigned short* Wt1l = Wt1 + (size_t)l * 512 * 1024;
    const unsigned short* Wt2l = Wt2 + (size_t)l * 512 * 1024;
    // ---- SAGE 1
    gemm_mfma<<<mgrid, 512, 0, stream>>>(B0, 512, 512, 1, Wt1l + 512, 1024,
                                         nullptr, B2, N_NODES);        // Yb = h@Wb1
    gemm_mfma<<<mgrid, 512, 0, stream>>>(B0, 512, 512, 1, Wt1l, 1024,
                                         b1 + l * 512, B1, N_NODES);   // Ya = h@Wa1+b
    aggr_norm<<<ngrid, 256, 0, stream>>>(B1, B2, rowptr, esrc, invdeg, N_NODES);
    hipMemsetAsync(sums, 0, 1024 * sizeof(float), stream);
    bn_stats<<<(N_NODES + 127) / 128, 256, 0, stream>>>(B1, N_NODES, sums);
    bn_apply<<<egrid, 256, 0, stream>>>(B1, B1, sums, g1 + l * 512,
                                        be1 + l * 512, N_NODES, 0);
    // ---- SAGE 2 + residual
    gemm_mfma<<<mgrid, 512, 0, stream>>>(B1, 512, 512, 1, Wt2l + 512, 1024,
                                         nullptr, B2, N_NODES);        // Yb
    gemm_mfma<<<mgrid, 512, 0, stream>>>(B1, 512, 512, 1, Wt2l, 1024,
                                         b2 + l * 512, B1, N_NODES);   // in-place, safe
    aggr_norm<<<ngrid, 256, 0, stream>>>(B1, B2, rowptr, esrc, invdeg, N_NODES);
    hipMemsetAsync(sums, 0, 1024 * sizeof(float), stream);
    bn_stats<<<(N_NODES + 127) / 128, 256, 0, stream>>>(B1, N_NODES, sums);
    bn_apply<<<egrid, 256, 0, stream>>>(B1, B0, sums, g2 + l * 512,
                                        be2 + l * 512, N_NODES, 1);
  }

  // ---- pooling + readout
  hipMemsetAsync(hg, 0, (size_t)N_GRAPH * HID * sizeof(float), stream);
  hipMemsetAsync(bcnt, 0, N_GRAPH * sizeof(float), stream);
  bcount<<<(N_NODES + 255) / 256, 256, 0, stream>>>(batch, bcnt, N_NODES);
  att_pool2<<<(N_NODES + 255) / 256, 256, 0, stream>>>(B0, batch, Watt, hg, N_NODES);
  readout<<<dim3(N_GRAPH, 4), 256, 0, stream>>>(hg, bcnt, Wread, out);
}